// Round 1
// baseline (467.747 us; speedup 1.0000x reference)
//
#include <hip/hip_runtime.h>
#include <math.h>

#define BS 64
#define NOBJ 256
#define TTOK 32
#define DIM 512
#define NREL 8
#define DKK 64
#define NN 65536

typedef __attribute__((ext_vector_type(8))) short bf16x8;
typedef __attribute__((ext_vector_type(4))) float f32x4;

__device__ __forceinline__ unsigned short f2bf(float x) {
    union { float f; unsigned int u; } c; c.f = x;
    unsigned int u = c.u;
    return (unsigned short)((u + 0x7fffu + ((u >> 16) & 1u)) >> 16);
}
__device__ __forceinline__ float bf2f(unsigned short h) {
    union { unsigned int u; float f; } c; c.u = ((unsigned int)h) << 16;
    return c.f;
}
// async 16B global -> LDS (wave-uniform LDS base + lane*16)
__device__ __forceinline__ void gl2lds16(const unsigned short* g, unsigned short* l) {
    __builtin_amdgcn_global_load_lds((const __attribute__((address_space(1))) void*)g,
                                     (__attribute__((address_space(3))) void*)l, 16, 0, 0);
}

// ---------------- K1: text summary -> t_summary (bf16, 64x512) ----------------
__global__ void k_text(const float* __restrict__ tt, const float* __restrict__ t_mask,
                       const float* __restrict__ tc_w, const float* __restrict__ tc_b,
                       unsigned short* __restrict__ ts_bf) {
    int b = blockIdx.x;
    int tid = threadIdx.x;
    __shared__ float red[TTOK][8];
    __shared__ float sc[TTOK];
    {
        int tok = tid >> 3, seg = tid & 7;
        const float* tp = tt + (size_t)(b * TTOK + tok) * DIM + seg * 64;
        const float* wp = tc_w + seg * 64;
        float s = 0.f;
#pragma unroll
        for (int i = 0; i < 16; ++i) {
            float4 a = *(const float4*)(tp + i * 4);
            float4 w = *(const float4*)(wp + i * 4);
            s += a.x * w.x + a.y * w.y + a.z * w.z + a.w * w.w;
        }
        red[tok][seg] = s;
    }
    __syncthreads();
    if (tid < TTOK) {
        float s = 0.f;
#pragma unroll
        for (int i = 0; i < 8; ++i) s += red[tid][i];
        float m = t_mask[b * TTOK + tid];
        float tc = m * s + tc_b[0];
        float sig = 1.f / (1.f + __expf(-tc));
        sc[tid] = (m != 0.f) ? m * sig : 0.f;
    }
    __syncthreads();
    for (int d = tid; d < DIM; d += 256) {
        float acc = 0.f;
#pragma unroll
        for (int tok = 0; tok < TTOK; ++tok)
            acc += tt[(size_t)(b * TTOK + tok) * DIM + d] * sc[tok];
        ts_bf[b * DIM + d] = f2bf(acc);
    }
}

// ---------------- K3a: convert v,b to bf16 ----------------
__global__ void k_convert(const float* __restrict__ v, const float* __restrict__ b,
                          unsigned short* __restrict__ v_bf, unsigned short* __restrict__ b_bf) {
    const float* src = blockIdx.y ? b : v;
    unsigned short* dst = blockIdx.y ? b_bf : v_bf;
    size_t i = ((size_t)blockIdx.x * 256 + threadIdx.x) * 4;
    float4 a = *(const float4*)(src + i);
    ushort4 o;
    o.x = f2bf(a.x); o.y = f2bf(a.y); o.z = f2bf(a.z); o.w = f2bf(a.w);
    *(ushort4*)(dst + i) = o;
}

// ---------------- K3b: weights -> WT (2560 cols x 512 k, bf16, k-contiguous) ----------------
__global__ void k_wt(const float* __restrict__ w0, const float* __restrict__ w1,
                     const float* __restrict__ w2, const float* __restrict__ w3,
                     const float* __restrict__ w4, unsigned short* __restrict__ WT) {
    int wsel = blockIdx.z;
    const float* W = wsel == 0 ? w0 : wsel == 1 ? w1 : wsel == 2 ? w2 : wsel == 3 ? w3 : w4;
    int k0 = blockIdx.x * 64, d0 = blockIdx.y * 64;
    __shared__ float tile[64][65];
    int tid = threadIdx.x;
#pragma unroll
    for (int p = 0; p < 16; ++p) {
        int lin = p * 256 + tid;
        int kk = lin >> 6, dd = lin & 63;
        tile[kk][dd] = W[(size_t)(k0 + kk) * DIM + d0 + dd];
    }
    __syncthreads();
    unsigned short* outp = WT + (size_t)wsel * DIM * DIM;
#pragma unroll
    for (int p = 0; p < 16; ++p) {
        int lin = p * 256 + tid;
        int dd = lin >> 6, kk = lin & 63;
        outp[(size_t)(d0 + dd) * DIM + k0 + kk] = f2bf(tile[kk][dd]);
    }
}

// ---------------- K2: tmap = relu(ts @ tmap_w + tmap_b), (64 x 65536) -> bf16 ----------------
__launch_bounds__(256)
__global__ void k_tmap(const unsigned short* __restrict__ ts_bf,
                       const float* __restrict__ tmap_w, const float* __restrict__ tmap_b,
                       unsigned short* __restrict__ tmap) {
    int j0 = blockIdx.x * 64;
    int tid = threadIdx.x;
    int w = tid >> 6, lane = tid & 63, q = lane >> 4, li = lane & 15;
    __shared__ __align__(16) unsigned short Bt[64][40];
    f32x4 acc[4];
#pragma unroll
    for (int ct = 0; ct < 4; ++ct) acc[ct] = (f32x4){0.f, 0.f, 0.f, 0.f};

    for (int ks = 0; ks < 16; ++ks) {
        int k0 = ks * 32;
#pragma unroll
        for (int p = 0; p < 8; ++p) {
            int kk = (tid >> 6) + p * 4;
            int c = tid & 63;
            Bt[c][kk] = f2bf(tmap_w[(size_t)(k0 + kk) * NN + j0 + c]);
        }
        __syncthreads();
        bf16x8 a = *(const bf16x8*)(ts_bf + (size_t)(w * 16 + li) * DIM + k0 + q * 8);
#pragma unroll
        for (int ct = 0; ct < 4; ++ct) {
            bf16x8 bb = *(const bf16x8*)(&Bt[ct * 16 + li][q * 8]);
            acc[ct] = __builtin_amdgcn_mfma_f32_16x16x32_bf16(a, bb, acc[ct], 0, 0, 0);
        }
        __syncthreads();
    }
#pragma unroll
    for (int ct = 0; ct < 4; ++ct) {
        int j = j0 + ct * 16 + li;
        float bias = tmap_b[j];
#pragma unroll
        for (int i = 0; i < 4; ++i) {
            int bb = w * 16 + q * 4 + i;
            float val = fmaxf(acc[ct][i] + bias, 0.f);
            tmap[(size_t)bb * NN + j] = f2bf(val);
        }
    }
}

// ---------------- K4: 5 projections, BK=64, swizzled DMA staging, coalesced epilogue ----------
__launch_bounds__(256)
__global__ void k_proj(const unsigned short* __restrict__ v_bf, const unsigned short* __restrict__ b_bf,
                       const unsigned short* __restrict__ WT,
                       const float* __restrict__ bias0, const float* __restrict__ bias1,
                       const float* __restrict__ bias2, const float* __restrict__ bias3,
                       const float* __restrict__ bias4, const float* __restrict__ v_mask,
                       unsigned short* __restrict__ wg1, unsigned short* __restrict__ wg2,
                       unsigned short* __restrict__ wk, unsigned short* __restrict__ wq,
                       unsigned short* __restrict__ wvT) {
    int bx = blockIdx.x;
    int by = blockIdx.y;
    int m0 = bx * 128;
    int wsel = by >> 2;
    const unsigned short* A = (wsel < 2) ? b_bf : v_bf;
    int tid = threadIdx.x;
    int w = tid >> 6, lane = tid & 63, q = lane >> 4, li = lane & 15;
    int rh = w & 1, ch = w >> 1;

    __shared__ __align__(16) unsigned short smem[128 * 136];
    unsigned short* As = smem;
    unsigned short* Bs = smem + 8192;

    f32x4 acc[4][4];
#pragma unroll
    for (int rt = 0; rt < 4; ++rt)
#pragma unroll
        for (int ct = 0; ct < 4; ++ct) acc[rt][ct] = (f32x4){0.f, 0.f, 0.f, 0.f};

    const unsigned short* WTb = WT + (size_t)by * 128 * DIM;

    int rl = lane >> 3;
    int lseg = (lane & 7) ^ rl;
    const unsigned short* Agp[4];
    const unsigned short* Bgp[4];
    unsigned short* Alp[4];
    unsigned short* Blp[4];
#pragma unroll
    for (int c4 = 0; c4 < 4; ++c4) {
        int c = w * 4 + c4;
        int row = c * 8 + rl;
        Agp[c4] = A + (size_t)(m0 + row) * DIM + lseg * 8;
        Bgp[c4] = WTb + (size_t)row * DIM + lseg * 8;
        Alp[c4] = As + c * 512;
        Blp[c4] = Bs + c * 512;
    }

    int arow = (rh * 64 + li) * 64;
    int brow = (ch * 64 + li) * 64;
    int sseg0 = ((q) ^ (li & 7)) * 8;
    int sseg1 = ((4 + q) ^ (li & 7)) * 8;

    for (int ks = 0; ks < 8; ++ks) {
        int k0 = ks * 64;
#pragma unroll
        for (int c4 = 0; c4 < 4; ++c4) {
            gl2lds16(Agp[c4] + k0, Alp[c4]);
            gl2lds16(Bgp[c4] + k0, Blp[c4]);
        }
        __syncthreads();
#pragma unroll
        for (int j = 0; j < 2; ++j) {
            int sseg = j ? sseg1 : sseg0;
            bf16x8 af[4], bfr[4];
#pragma unroll
            for (int rt = 0; rt < 4; ++rt)
                af[rt] = *(const bf16x8*)(As + arow + rt * 1024 + sseg);
#pragma unroll
            for (int ct = 0; ct < 4; ++ct)
                bfr[ct] = *(const bf16x8*)(Bs + brow + ct * 1024 + sseg);
#pragma unroll
            for (int rt = 0; rt < 4; ++rt)
#pragma unroll
                for (int ct = 0; ct < 4; ++ct)
                    acc[rt][ct] = __builtin_amdgcn_mfma_f32_16x16x32_bf16(af[rt], bfr[ct], acc[rt][ct], 0, 0, 0);
        }
        __syncthreads();
    }

    const float* bias = wsel == 0 ? bias0 : wsel == 1 ? bias1 : wsel == 2 ? bias2 : wsel == 3 ? bias3 : bias4;
    int dblk = (by & 3) * 128;

    unsigned short (*T)[136] = (unsigned short (*)[136])smem;
    if (wsel < 4) {
#pragma unroll
        for (int ct = 0; ct < 4; ++ct) {
            int d = dblk + ch * 64 + ct * 16 + li;
            float bs = bias[d];
#pragma unroll
            for (int rt = 0; rt < 4; ++rt) {
#pragma unroll
                for (int i = 0; i < 4; ++i) {
                    int nl = rh * 64 + rt * 16 + q * 4 + i;
                    float val = acc[rt][ct][i] + bs;
                    if (wsel < 2) val *= v_mask[m0 + nl];
                    T[nl][ch * 64 + ct * 16 + li] = f2bf(val);
                }
            }
        }
        __syncthreads();
        unsigned short* dstb = wsel == 0 ? wg1 : wsel == 1 ? wg2 : wsel == 2 ? wk : wq;
        int dc = lane & 15;
#pragma unroll
        for (int rr = 0; rr < 8; ++rr) {
            int outer = w * 32 + rr * 4 + (lane >> 4);
            *(bf16x8*)(dstb + (size_t)(m0 + outer) * DIM + dblk + dc * 8) =
                *(const bf16x8*)(&T[outer][dc * 8]);
        }
    } else {
#pragma unroll
        for (int ct = 0; ct < 4; ++ct) {
            int dl = ch * 64 + ct * 16 + li;
            float bs = bias[dblk + dl];
#pragma unroll
            for (int rt = 0; rt < 4; ++rt) {
#pragma unroll
                for (int i = 0; i < 4; ++i) {
                    int nl = rh * 64 + rt * 16 + q * 4 + i;
                    T[dl][nl] = f2bf(acc[rt][ct][i] + bs);
                }
            }
        }
        __syncthreads();
        int b = m0 >> 8, nbase = m0 & 255;
        int dc = lane & 15;
#pragma unroll
        for (int rr = 0; rr < 8; ++rr) {
            int outer = w * 32 + rr * 4 + (lane >> 4);
            int d = dblk + outer;
            int r = d >> 6, dk = d & 63;
            *(bf16x8*)(wvT + ((size_t)(b * NREL + r) * DKK + dk) * NOBJ + nbase + dc * 8) =
                *(const bf16x8*)(&T[outer][dc * 8]);
        }
    }
}

// ---------------- K5: attention, p = g_clamped * exp(dot/8) identity (no log, no online max) ----
// Grid 2048: XCD-swizzled decode; block = (b, r, quarter of 64 rows). 4 waves x 16 rows.
// Latency-bound kernel: doubled block count (8 blocks/CU) for TLP; vb/tmap loads hoisted
// to top of j-loop so VMEM latency overlaps the QK MFMAs.
__launch_bounds__(256)
__global__ void k_attn(const unsigned short* __restrict__ wg1, const unsigned short* __restrict__ wg2,
                       const unsigned short* __restrict__ wk, const unsigned short* __restrict__ wq,
                       const unsigned short* __restrict__ wvT,
                       const unsigned short* __restrict__ tmap, const float* __restrict__ v_mask,
                       const float* __restrict__ v, float* __restrict__ out) {
    int L = blockIdx.x;
    int x = L & 7, jj = L >> 3;
    int b = x + 8 * (jj >> 5);           // same-b blocks share launch-id mod 8 (XCD locality)
    int inner = jj & 31;
    int r = inner >> 2, qtr = inner & 3;
    int br = b * NREL + r;

    int tid = threadIdx.x;
    int w = tid >> 6, lane = tid & 63, q = lane >> 4, li = lane & 15;
    int n0 = qtr * 64 + w * 16;          // wave's 16 rows

    __shared__ __align__(16) unsigned short P_lds[4][16][36];

    // A-fragments: wg1/wk rows (16 x 64k)
    bf16x8 ag[2], ak[2];
    {
        const unsigned short* g1b = wg1 + (size_t)(b * NOBJ + n0 + li) * DIM + r * DKK + q * 8;
        const unsigned short* kb  = wk  + (size_t)(b * NOBJ + n0 + li) * DIM + r * DKK + q * 8;
#pragma unroll
        for (int kt = 0; kt < 2; ++kt) {
            ag[kt] = *(const bf16x8*)(g1b + kt * 32);
            ak[kt] = *(const bf16x8*)(kb + kt * 32);
        }
    }

    f32x4 O[4];
    float lsum[4];
#pragma unroll
    for (int dt = 0; dt < 4; ++dt) O[dt] = (f32x4){0.f, 0.f, 0.f, 0.f};
#pragma unroll
    for (int i = 0; i < 4; ++i) lsum[i] = 0.f;

    const unsigned short* tb = tmap + ((size_t)b << 16) + (n0 + q * 4) * 256 + li;

    for (int j = 0; j < 8; ++j) {
        int c0 = j * 32;
        // ---- all loads for this iteration issued up front ----
        bf16x8 bg[2][2], bq[2][2], vb[4];
        {
            const unsigned short* g2b = wg2 + (size_t)(b * NOBJ + c0 + li) * DIM + r * DKK + q * 8;
            const unsigned short* qb  = wq  + (size_t)(b * NOBJ + c0 + li) * DIM + r * DKK + q * 8;
#pragma unroll
            for (int ct = 0; ct < 2; ++ct)
#pragma unroll
                for (int kt = 0; kt < 2; ++kt) {
                    bg[ct][kt] = *(const bf16x8*)(g2b + (size_t)ct * 16 * DIM + kt * 32);
                    bq[ct][kt] = *(const bf16x8*)(qb + (size_t)ct * 16 * DIM + kt * 32);
                }
        }
#pragma unroll
        for (int dt = 0; dt < 4; ++dt)
            vb[dt] = *(const bf16x8*)(wvT + (size_t)(br * DKK + dt * 16 + li) * NOBJ + c0 + q * 8);
        float tmv[2][4];
#pragma unroll
        for (int ct = 0; ct < 2; ++ct)
#pragma unroll
            for (int i = 0; i < 4; ++i)
                tmv[ct][i] = bf2f(tb[i * 256 + c0 + ct * 16]);
        float vm0 = v_mask[b * NOBJ + c0 + li];
        float vm1 = v_mask[b * NOBJ + c0 + 16 + li];

        // ---- QK^T + G-score -> p -> P_lds ----
#pragma unroll
        for (int ct = 0; ct < 2; ++ct) {
            f32x4 aG = (f32x4){0.f, 0.f, 0.f, 0.f};
            f32x4 aK = (f32x4){0.f, 0.f, 0.f, 0.f};
#pragma unroll
            for (int kt = 0; kt < 2; ++kt) {
                aG = __builtin_amdgcn_mfma_f32_16x16x32_bf16(ag[kt], bg[ct][kt], aG, 0, 0, 0);
                aK = __builtin_amdgcn_mfma_f32_16x16x32_bf16(ak[kt], bq[ct][kt], aK, 0, 0, 0);
            }
            float vm = ct ? vm1 : vm0;
#pragma unroll
            for (int i = 0; i < 4; ++i) {
                // p = max(relu(G)+tmap, 1e-6) * exp(dot/8); exact softmax after /l.
                float g = fmaxf(fmaxf(aG[i], 0.f) + tmv[ct][i], 1e-6f);
                float p = (vm == 0.f) ? 0.f : g * __expf(aK[i] * 0.125f);
                lsum[i] += p;
                P_lds[w][q * 4 + i][ct * 16 + li] = f2bf(p);
            }
        }
        // ---- PV ----
        bf16x8 pa = *(const bf16x8*)(&P_lds[w][li][q * 8]);
#pragma unroll
        for (int dt = 0; dt < 4; ++dt)
            O[dt] = __builtin_amdgcn_mfma_f32_16x16x32_bf16(pa, vb[dt], O[dt], 0, 0, 0);
    }

    // epilogue: reduce l over the 16 li lanes, then out = O/l + v
    float linv[4];
#pragma unroll
    for (int i = 0; i < 4; ++i) {
        float s = lsum[i];
        s += __shfl_xor(s, 1);
        s += __shfl_xor(s, 2);
        s += __shfl_xor(s, 4);
        s += __shfl_xor(s, 8);
        linv[i] = 1.f / s;
    }
#pragma unroll
    for (int dt = 0; dt < 4; ++dt) {
#pragma unroll
        for (int i = 0; i < 4; ++i) {
            int n = n0 + q * 4 + i;
            size_t idx = (size_t)(b * NOBJ + n) * DIM + r * DKK + dt * 16 + li;
            out[idx] = O[dt][i] * linv[i] + v[idx];
        }
    }
}

extern "C" void kernel_launch(void* const* d_in, const int* in_sizes, int n_in,
                              void* d_out, int out_size, void* d_ws, size_t ws_size,
                              hipStream_t stream) {
    const float* v      = (const float*)d_in[0];
    const float* b      = (const float*)d_in[1];
    const float* v_mask = (const float*)d_in[2];
    const float* t      = (const float*)d_in[3];
    const float* t_mask = (const float*)d_in[4];
    const float* WG1_w  = (const float*)d_in[5];
    const float* WG1_b  = (const float*)d_in[6];
    const float* WG2_w  = (const float*)d_in[7];
    const float* WG2_b  = (const float*)d_in[8];
    const float* WK_w   = (const float*)d_in[9];
    const float* WK_b   = (const float*)d_in[10];
    const float* WQ_w   = (const float*)d_in[11];
    const float* WQ_b   = (const float*)d_in[12];
    const float* WV_w   = (const float*)d_in[13];
    const float* WV_b   = (const float*)d_in[14];
    const float* tc_w   = (const float*)d_in[15];
    const float* tc_b   = (const float*)d_in[16];
    const float* tmap_w = (const float*)d_in[17];
    const float* tmap_b = (const float*)d_in[18];
    float* out = (float*)d_out;

    char* ws = (char*)d_ws;
    size_t off = 0;
    auto alloc = [&](size_t bytes) {
        void* p = ws + off;
        off += (bytes + 255) & ~(size_t)255;
        return p;
    };
    unsigned short* ts_bf = (unsigned short*)alloc((size_t)BS * DIM * 2);
    unsigned short* tmap  = (unsigned short*)alloc((size_t)BS * NN * 2);
    unsigned short* v_bf  = (unsigned short*)alloc((size_t)BS * NOBJ * DIM * 2);
    unsigned short* b_bf  = (unsigned short*)alloc((size_t)BS * NOBJ * DIM * 2);
    unsigned short* WT    = (unsigned short*)alloc((size_t)5 * DIM * DIM * 2);
    unsigned short* wg1   = (unsigned short*)alloc((size_t)BS * NOBJ * DIM * 2);
    unsigned short* wg2   = (unsigned short*)alloc((size_t)BS * NOBJ * DIM * 2);
    unsigned short* wk    = (unsigned short*)alloc((size_t)BS * NOBJ * DIM * 2);
    unsigned short* wq    = (unsigned short*)alloc((size_t)BS * NOBJ * DIM * 2);
    unsigned short* wvT   = (unsigned short*)alloc((size_t)BS * NOBJ * DIM * 2);

    k_text<<<dim3(BS), dim3(256), 0, stream>>>(t, t_mask, tc_w, tc_b, ts_bf);
    k_convert<<<dim3(8192, 2), dim3(256), 0, stream>>>(v, b, v_bf, b_bf);
    k_wt<<<dim3(8, 8, 5), dim3(256), 0, stream>>>(WG1_w, WG2_w, WK_w, WQ_w, WV_w, WT);
    k_tmap<<<dim3(1024), dim3(256), 0, stream>>>(ts_bf, tmap_w, tmap_b, tmap);
    k_proj<<<dim3(128, 20), dim3(256), 0, stream>>>(v_bf, b_bf, WT,
                                                    WG1_b, WG2_b, WK_b, WQ_b, WV_b, v_mask,
                                                    wg1, wg2, wk, wq, wvT);
    k_attn<<<dim3(2048), dim3(256), 0, stream>>>(wg1, wg2, wk, wq, wvT, tmap, v_mask, v, out);
}

// Round 2
// 439.515 us; speedup vs baseline: 1.0642x; 1.0642x over previous
//
#include <hip/hip_runtime.h>
#include <math.h>

#define BS 64
#define NOBJ 256
#define TTOK 32
#define DIM 512
#define NREL 8
#define DKK 64
#define NN 65536

typedef __attribute__((ext_vector_type(8))) short bf16x8;
typedef __attribute__((ext_vector_type(4))) float f32x4;

__device__ __forceinline__ unsigned short f2bf(float x) {
    union { float f; unsigned int u; } c; c.f = x;
    unsigned int u = c.u;
    return (unsigned short)((u + 0x7fffu + ((u >> 16) & 1u)) >> 16);
}
__device__ __forceinline__ float bf2f(unsigned short h) {
    union { unsigned int u; float f; } c; c.u = ((unsigned int)h) << 16;
    return c.f;
}
// async 16B global -> LDS (wave-uniform LDS base + lane*16)
__device__ __forceinline__ void gl2lds16(const unsigned short* g, unsigned short* l) {
    __builtin_amdgcn_global_load_lds((const __attribute__((address_space(1))) void*)g,
                                     (__attribute__((address_space(3))) void*)l, 16, 0, 0);
}

// ---------------- K1: text summary -> t_summary (bf16, 64x512) ----------------
__global__ void k_text(const float* __restrict__ tt, const float* __restrict__ t_mask,
                       const float* __restrict__ tc_w, const float* __restrict__ tc_b,
                       unsigned short* __restrict__ ts_bf) {
    int b = blockIdx.x;
    int tid = threadIdx.x;
    __shared__ float red[TTOK][8];
    __shared__ float sc[TTOK];
    {
        int tok = tid >> 3, seg = tid & 7;
        const float* tp = tt + (size_t)(b * TTOK + tok) * DIM + seg * 64;
        const float* wp = tc_w + seg * 64;
        float s = 0.f;
#pragma unroll
        for (int i = 0; i < 16; ++i) {
            float4 a = *(const float4*)(tp + i * 4);
            float4 w = *(const float4*)(wp + i * 4);
            s += a.x * w.x + a.y * w.y + a.z * w.z + a.w * w.w;
        }
        red[tok][seg] = s;
    }
    __syncthreads();
    if (tid < TTOK) {
        float s = 0.f;
#pragma unroll
        for (int i = 0; i < 8; ++i) s += red[tid][i];
        float m = t_mask[b * TTOK + tid];
        float tc = m * s + tc_b[0];
        float sig = 1.f / (1.f + __expf(-tc));
        sc[tid] = (m != 0.f) ? m * sig : 0.f;
    }
    __syncthreads();
    for (int d = tid; d < DIM; d += 256) {
        float acc = 0.f;
#pragma unroll
        for (int tok = 0; tok < TTOK; ++tok)
            acc += tt[(size_t)(b * TTOK + tok) * DIM + d] * sc[tok];
        ts_bf[b * DIM + d] = f2bf(acc);
    }
}

// ---------------- K3a: convert v,b to bf16 ----------------
__global__ void k_convert(const float* __restrict__ v, const float* __restrict__ b,
                          unsigned short* __restrict__ v_bf, unsigned short* __restrict__ b_bf) {
    const float* src = blockIdx.y ? b : v;
    unsigned short* dst = blockIdx.y ? b_bf : v_bf;
    size_t i = ((size_t)blockIdx.x * 256 + threadIdx.x) * 4;
    float4 a = *(const float4*)(src + i);
    ushort4 o;
    o.x = f2bf(a.x); o.y = f2bf(a.y); o.z = f2bf(a.z); o.w = f2bf(a.w);
    *(ushort4*)(dst + i) = o;
}

// ---------------- K3b: weights -> WT (2560 cols x 512 k, bf16, k-contiguous) ----------------
__global__ void k_wt(const float* __restrict__ w0, const float* __restrict__ w1,
                     const float* __restrict__ w2, const float* __restrict__ w3,
                     const float* __restrict__ w4, unsigned short* __restrict__ WT) {
    int wsel = blockIdx.z;
    const float* W = wsel == 0 ? w0 : wsel == 1 ? w1 : wsel == 2 ? w2 : wsel == 3 ? w3 : w4;
    int k0 = blockIdx.x * 64, d0 = blockIdx.y * 64;
    __shared__ float tile[64][65];
    int tid = threadIdx.x;
#pragma unroll
    for (int p = 0; p < 16; ++p) {
        int lin = p * 256 + tid;
        int kk = lin >> 6, dd = lin & 63;
        tile[kk][dd] = W[(size_t)(k0 + kk) * DIM + d0 + dd];
    }
    __syncthreads();
    unsigned short* outp = WT + (size_t)wsel * DIM * DIM;
#pragma unroll
    for (int p = 0; p < 16; ++p) {
        int lin = p * 256 + tid;
        int dd = lin >> 6, kk = lin & 63;
        outp[(size_t)(d0 + dd) * DIM + k0 + kk] = f2bf(tile[kk][dd]);
    }
}

// ---------------- K2: tmap = relu(ts @ tmap_w + tmap_b), (64 x 65536) -> bf16 ----------------
__launch_bounds__(256)
__global__ void k_tmap(const unsigned short* __restrict__ ts_bf,
                       const float* __restrict__ tmap_w, const float* __restrict__ tmap_b,
                       unsigned short* __restrict__ tmap) {
    int j0 = blockIdx.x * 64;
    int tid = threadIdx.x;
    int w = tid >> 6, lane = tid & 63, q = lane >> 4, li = lane & 15;
    __shared__ __align__(16) unsigned short Bt[64][40];
    f32x4 acc[4];
#pragma unroll
    for (int ct = 0; ct < 4; ++ct) acc[ct] = (f32x4){0.f, 0.f, 0.f, 0.f};

    for (int ks = 0; ks < 16; ++ks) {
        int k0 = ks * 32;
#pragma unroll
        for (int p = 0; p < 8; ++p) {
            int kk = (tid >> 6) + p * 4;
            int c = tid & 63;
            Bt[c][kk] = f2bf(tmap_w[(size_t)(k0 + kk) * NN + j0 + c]);
        }
        __syncthreads();
        bf16x8 a = *(const bf16x8*)(ts_bf + (size_t)(w * 16 + li) * DIM + k0 + q * 8);
#pragma unroll
        for (int ct = 0; ct < 4; ++ct) {
            bf16x8 bb = *(const bf16x8*)(&Bt[ct * 16 + li][q * 8]);
            acc[ct] = __builtin_amdgcn_mfma_f32_16x16x32_bf16(a, bb, acc[ct], 0, 0, 0);
        }
        __syncthreads();
    }
#pragma unroll
    for (int ct = 0; ct < 4; ++ct) {
        int j = j0 + ct * 16 + li;
        float bias = tmap_b[j];
#pragma unroll
        for (int i = 0; i < 4; ++i) {
            int bb = w * 16 + q * 4 + i;
            float val = fmaxf(acc[ct][i] + bias, 0.f);
            tmap[(size_t)bb * NN + j] = f2bf(val);
        }
    }
}

// ---------------- K4: 5 projections, BK=64, swizzled DMA staging, coalesced epilogue ----------
__launch_bounds__(256)
__global__ void k_proj(const unsigned short* __restrict__ v_bf, const unsigned short* __restrict__ b_bf,
                       const unsigned short* __restrict__ WT,
                       const float* __restrict__ bias0, const float* __restrict__ bias1,
                       const float* __restrict__ bias2, const float* __restrict__ bias3,
                       const float* __restrict__ bias4, const float* __restrict__ v_mask,
                       unsigned short* __restrict__ wg1, unsigned short* __restrict__ wg2,
                       unsigned short* __restrict__ wk, unsigned short* __restrict__ wq,
                       unsigned short* __restrict__ wvT) {
    int bx = blockIdx.x;
    int by = blockIdx.y;
    int m0 = bx * 128;
    int wsel = by >> 2;
    const unsigned short* A = (wsel < 2) ? b_bf : v_bf;
    int tid = threadIdx.x;
    int w = tid >> 6, lane = tid & 63, q = lane >> 4, li = lane & 15;
    int rh = w & 1, ch = w >> 1;

    __shared__ __align__(16) unsigned short smem[128 * 136];
    unsigned short* As = smem;
    unsigned short* Bs = smem + 8192;

    f32x4 acc[4][4];
#pragma unroll
    for (int rt = 0; rt < 4; ++rt)
#pragma unroll
        for (int ct = 0; ct < 4; ++ct) acc[rt][ct] = (f32x4){0.f, 0.f, 0.f, 0.f};

    const unsigned short* WTb = WT + (size_t)by * 128 * DIM;

    int rl = lane >> 3;
    int lseg = (lane & 7) ^ rl;
    const unsigned short* Agp[4];
    const unsigned short* Bgp[4];
    unsigned short* Alp[4];
    unsigned short* Blp[4];
#pragma unroll
    for (int c4 = 0; c4 < 4; ++c4) {
        int c = w * 4 + c4;
        int row = c * 8 + rl;
        Agp[c4] = A + (size_t)(m0 + row) * DIM + lseg * 8;
        Bgp[c4] = WTb + (size_t)row * DIM + lseg * 8;
        Alp[c4] = As + c * 512;
        Blp[c4] = Bs + c * 512;
    }

    int arow = (rh * 64 + li) * 64;
    int brow = (ch * 64 + li) * 64;
    int sseg0 = ((q) ^ (li & 7)) * 8;
    int sseg1 = ((4 + q) ^ (li & 7)) * 8;

    for (int ks = 0; ks < 8; ++ks) {
        int k0 = ks * 64;
#pragma unroll
        for (int c4 = 0; c4 < 4; ++c4) {
            gl2lds16(Agp[c4] + k0, Alp[c4]);
            gl2lds16(Bgp[c4] + k0, Blp[c4]);
        }
        __syncthreads();
#pragma unroll
        for (int j = 0; j < 2; ++j) {
            int sseg = j ? sseg1 : sseg0;
            bf16x8 af[4], bfr[4];
#pragma unroll
            for (int rt = 0; rt < 4; ++rt)
                af[rt] = *(const bf16x8*)(As + arow + rt * 1024 + sseg);
#pragma unroll
            for (int ct = 0; ct < 4; ++ct)
                bfr[ct] = *(const bf16x8*)(Bs + brow + ct * 1024 + sseg);
#pragma unroll
            for (int rt = 0; rt < 4; ++rt)
#pragma unroll
                for (int ct = 0; ct < 4; ++ct)
                    acc[rt][ct] = __builtin_amdgcn_mfma_f32_16x16x32_bf16(af[rt], bfr[ct], acc[rt][ct], 0, 0, 0);
        }
        __syncthreads();
    }

    const float* bias = wsel == 0 ? bias0 : wsel == 1 ? bias1 : wsel == 2 ? bias2 : wsel == 3 ? bias3 : bias4;
    int dblk = (by & 3) * 128;

    unsigned short (*T)[136] = (unsigned short (*)[136])smem;
    if (wsel < 4) {
#pragma unroll
        for (int ct = 0; ct < 4; ++ct) {
            int d = dblk + ch * 64 + ct * 16 + li;
            float bs = bias[d];
#pragma unroll
            for (int rt = 0; rt < 4; ++rt) {
#pragma unroll
                for (int i = 0; i < 4; ++i) {
                    int nl = rh * 64 + rt * 16 + q * 4 + i;
                    float val = acc[rt][ct][i] + bs;
                    if (wsel < 2) val *= v_mask[m0 + nl];
                    T[nl][ch * 64 + ct * 16 + li] = f2bf(val);
                }
            }
        }
        __syncthreads();
        unsigned short* dstb = wsel == 0 ? wg1 : wsel == 1 ? wg2 : wsel == 2 ? wk : wq;
        int dc = lane & 15;
#pragma unroll
        for (int rr = 0; rr < 8; ++rr) {
            int outer = w * 32 + rr * 4 + (lane >> 4);
            *(bf16x8*)(dstb + (size_t)(m0 + outer) * DIM + dblk + dc * 8) =
                *(const bf16x8*)(&T[outer][dc * 8]);
        }
    } else {
#pragma unroll
        for (int ct = 0; ct < 4; ++ct) {
            int dl = ch * 64 + ct * 16 + li;
            float bs = bias[dblk + dl];
#pragma unroll
            for (int rt = 0; rt < 4; ++rt) {
#pragma unroll
                for (int i = 0; i < 4; ++i) {
                    int nl = rh * 64 + rt * 16 + q * 4 + i;
                    T[dl][nl] = f2bf(acc[rt][ct][i] + bs);
                }
            }
        }
        __syncthreads();
        int b = m0 >> 8, nbase = m0 & 255;
        int dc = lane & 15;
#pragma unroll
        for (int rr = 0; rr < 8; ++rr) {
            int outer = w * 32 + rr * 4 + (lane >> 4);
            int d = dblk + outer;
            int r = d >> 6, dk = d & 63;
            *(bf16x8*)(wvT + ((size_t)(b * NREL + r) * DKK + dk) * NOBJ + nbase + dc * 8) =
                *(const bf16x8*)(&T[outer][dc * 8]);
        }
    }
}

// ---------------- K5: attention, software-pipelined (PV deferred one iteration) ----------
// Grid 1024 (known-good block shape): block = (b, r, half of 128 rows), 4 waves x 32 rows.
// Per iter j: loads(j) -> PV(j-1) [reads P_lds written a full iter ago, vb loaded a full
// iter ago] -> QK(j) -> softmax(j) -> P_lds[j&1] -> issue vb(j). Breaks the in-iteration
// ds_write->lgkmcnt->ds_read->MFMA serialization that dominated the latency chain.
__launch_bounds__(256)
__global__ void k_attn(const unsigned short* __restrict__ wg1, const unsigned short* __restrict__ wg2,
                       const unsigned short* __restrict__ wk, const unsigned short* __restrict__ wq,
                       const unsigned short* __restrict__ wvT,
                       const unsigned short* __restrict__ tmap, const float* __restrict__ v_mask,
                       const float* __restrict__ v, float* __restrict__ out) {
    int L = blockIdx.x;
    int x = L & 7, jj = L >> 3;
    int b = x + 8 * (jj >> 4);           // same-b blocks share launch-id mod 8 (XCD locality)
    int inner = jj & 15;
    int r = inner >> 1, half = inner & 1;
    int br = b * NREL + r;

    int tid = threadIdx.x;
    int w = tid >> 6, lane = tid & 63, q = lane >> 4, li = lane & 15;
    int n0 = half * 128 + w * 32;        // wave's 32 rows

    __shared__ __align__(16) unsigned short P_lds[4][2][32][36];

    // A-fragments: wg1/wk rows (32 x 64k)
    bf16x8 ag[2][2], ak[2][2];
    {
        const unsigned short* g1b = wg1 + (size_t)(b * NOBJ + n0 + li) * DIM + r * DKK + q * 8;
        const unsigned short* kb  = wk  + (size_t)(b * NOBJ + n0 + li) * DIM + r * DKK + q * 8;
#pragma unroll
        for (int rt = 0; rt < 2; ++rt)
#pragma unroll
            for (int kt = 0; kt < 2; ++kt) {
                ag[rt][kt] = *(const bf16x8*)(g1b + (size_t)rt * 16 * DIM + kt * 32);
                ak[rt][kt] = *(const bf16x8*)(kb + (size_t)rt * 16 * DIM + kt * 32);
            }
    }

    f32x4 O[2][4];
    float lsum[2][4];
#pragma unroll
    for (int rt = 0; rt < 2; ++rt) {
#pragma unroll
        for (int dt = 0; dt < 4; ++dt) O[rt][dt] = (f32x4){0.f, 0.f, 0.f, 0.f};
#pragma unroll
        for (int i = 0; i < 4; ++i) lsum[rt][i] = 0.f;
    }

    const unsigned short* tb = tmap + ((size_t)b << 16) + (n0 + q * 4) * 256 + li;

    bf16x8 vbp[4];                       // vb of iter j, consumed by PV at iter j+1

    // ---- QK+softmax body (emits P_lds[buf] for column tile c0) ----
    auto qk_softmax = [&](int j, int c0, int buf) {
        bf16x8 bg[2][2], bq[2][2];
        {
            const unsigned short* g2b = wg2 + (size_t)(b * NOBJ + c0 + li) * DIM + r * DKK + q * 8;
            const unsigned short* qb  = wq  + (size_t)(b * NOBJ + c0 + li) * DIM + r * DKK + q * 8;
#pragma unroll
            for (int ct = 0; ct < 2; ++ct)
#pragma unroll
                for (int kt = 0; kt < 2; ++kt) {
                    bg[ct][kt] = *(const bf16x8*)(g2b + (size_t)ct * 16 * DIM + kt * 32);
                    bq[ct][kt] = *(const bf16x8*)(qb + (size_t)ct * 16 * DIM + kt * 32);
                }
        }
        float vm0 = v_mask[b * NOBJ + c0 + li];
        float vm1 = v_mask[b * NOBJ + c0 + 16 + li];

#pragma unroll
        for (int rt = 0; rt < 2; ++rt) {
#pragma unroll
            for (int ct = 0; ct < 2; ++ct) {
                f32x4 aG = (f32x4){0.f, 0.f, 0.f, 0.f};
                f32x4 aK = (f32x4){0.f, 0.f, 0.f, 0.f};
#pragma unroll
                for (int kt = 0; kt < 2; ++kt) {
                    aG = __builtin_amdgcn_mfma_f32_16x16x32_bf16(ag[rt][kt], bg[ct][kt], aG, 0, 0, 0);
                    aK = __builtin_amdgcn_mfma_f32_16x16x32_bf16(ak[rt][kt], bq[ct][kt], aK, 0, 0, 0);
                }
                float vm = ct ? vm1 : vm0;
#pragma unroll
                for (int i = 0; i < 4; ++i) {
                    // p = max(relu(G)+tmap, 1e-6) * exp(dot/8); exact softmax after /l.
                    float tm = bf2f(tb[(rt * 16 + i) * 256 + c0 + ct * 16]);
                    float g = fmaxf(fmaxf(aG[i], 0.f) + tm, 1e-6f);
                    float p = (vm == 0.f) ? 0.f : g * __expf(aK[i] * 0.125f);
                    lsum[rt][i] += p;
                    P_lds[w][buf][rt * 16 + q * 4 + i][ct * 16 + li] = f2bf(p);
                }
            }
        }
    };
    // ---- vb issue for tile c0 (consumed next iteration) ----
    auto load_vb = [&](int c0) {
#pragma unroll
        for (int dt = 0; dt < 4; ++dt)
            vbp[dt] = *(const bf16x8*)(wvT + (size_t)(br * DKK + dt * 16 + li) * NOBJ + c0 + q * 8);
    };
    // ---- PV for tile whose P sits in P_lds[buf], vb in vbp ----
    auto pv = [&](int buf) {
        bf16x8 pa[2];
#pragma unroll
        for (int rt = 0; rt < 2; ++rt)
            pa[rt] = *(const bf16x8*)(&P_lds[w][buf][rt * 16 + li][q * 8]);
#pragma unroll
        for (int rt = 0; rt < 2; ++rt)
#pragma unroll
            for (int dt = 0; dt < 4; ++dt)
                O[rt][dt] = __builtin_amdgcn_mfma_f32_16x16x32_bf16(pa[rt], vbp[dt], O[rt][dt], 0, 0, 0);
    };

    // prologue: tile 0
    qk_softmax(0, 0, 0);
    load_vb(0);

    for (int j = 1; j < 8; ++j) {
        int c0 = j * 32;
        pv((j - 1) & 1);                 // PV(j-1): all operands one iteration old
        qk_softmax(j, c0, j & 1);
        load_vb(c0);
    }
    pv(1);                               // PV(7)

    // epilogue: reduce l over the 16 li lanes, then out = O/l + v
#pragma unroll
    for (int rt = 0; rt < 2; ++rt) {
        float linv[4];
#pragma unroll
        for (int i = 0; i < 4; ++i) {
            float s = lsum[rt][i];
            s += __shfl_xor(s, 1);
            s += __shfl_xor(s, 2);
            s += __shfl_xor(s, 4);
            s += __shfl_xor(s, 8);
            linv[i] = 1.f / s;
        }
#pragma unroll
        for (int dt = 0; dt < 4; ++dt) {
#pragma unroll
            for (int i = 0; i < 4; ++i) {
                int n = n0 + rt * 16 + q * 4 + i;
                size_t idx = (size_t)(b * NOBJ + n) * DIM + r * DKK + dt * 16 + li;
                out[idx] = O[rt][dt][i] * linv[i] + v[idx];
            }
        }
    }
}

extern "C" void kernel_launch(void* const* d_in, const int* in_sizes, int n_in,
                              void* d_out, int out_size, void* d_ws, size_t ws_size,
                              hipStream_t stream) {
    const float* v      = (const float*)d_in[0];
    const float* b      = (const float*)d_in[1];
    const float* v_mask = (const float*)d_in[2];
    const float* t      = (const float*)d_in[3];
    const float* t_mask = (const float*)d_in[4];
    const float* WG1_w  = (const float*)d_in[5];
    const float* WG1_b  = (const float*)d_in[6];
    const float* WG2_w  = (const float*)d_in[7];
    const float* WG2_b  = (const float*)d_in[8];
    const float* WK_w   = (const float*)d_in[9];
    const float* WK_b   = (const float*)d_in[10];
    const float* WQ_w   = (const float*)d_in[11];
    const float* WQ_b   = (const float*)d_in[12];
    const float* WV_w   = (const float*)d_in[13];
    const float* WV_b   = (const float*)d_in[14];
    const float* tc_w   = (const float*)d_in[15];
    const float* tc_b   = (const float*)d_in[16];
    const float* tmap_w = (const float*)d_in[17];
    const float* tmap_b = (const float*)d_in[18];
    float* out = (float*)d_out;

    char* ws = (char*)d_ws;
    size_t off = 0;
    auto alloc = [&](size_t bytes) {
        void* p = ws + off;
        off += (bytes + 255) & ~(size_t)255;
        return p;
    };
    unsigned short* ts_bf = (unsigned short*)alloc((size_t)BS * DIM * 2);
    unsigned short* tmap  = (unsigned short*)alloc((size_t)BS * NN * 2);
    unsigned short* v_bf  = (unsigned short*)alloc((size_t)BS * NOBJ * DIM * 2);
    unsigned short* b_bf  = (unsigned short*)alloc((size_t)BS * NOBJ * DIM * 2);
    unsigned short* WT    = (unsigned short*)alloc((size_t)5 * DIM * DIM * 2);
    unsigned short* wg1   = (unsigned short*)alloc((size_t)BS * NOBJ * DIM * 2);
    unsigned short* wg2   = (unsigned short*)alloc((size_t)BS * NOBJ * DIM * 2);
    unsigned short* wk    = (unsigned short*)alloc((size_t)BS * NOBJ * DIM * 2);
    unsigned short* wq    = (unsigned short*)alloc((size_t)BS * NOBJ * DIM * 2);
    unsigned short* wvT   = (unsigned short*)alloc((size_t)BS * NOBJ * DIM * 2);

    k_text<<<dim3(BS), dim3(256), 0, stream>>>(t, t_mask, tc_w, tc_b, ts_bf);
    k_convert<<<dim3(8192, 2), dim3(256), 0, stream>>>(v, b, v_bf, b_bf);
    k_wt<<<dim3(8, 8, 5), dim3(256), 0, stream>>>(WG1_w, WG2_w, WK_w, WQ_w, WV_w, WT);
    k_tmap<<<dim3(1024), dim3(256), 0, stream>>>(ts_bf, tmap_w, tmap_b, tmap);
    k_proj<<<dim3(128, 20), dim3(256), 0, stream>>>(v_bf, b_bf, WT,
                                                    WG1_b, WG2_b, WK_b, WQ_b, WV_b, v_mask,
                                                    wg1, wg2, wk, wq, wvT);
    k_attn<<<dim3(1024), dim3(256), 0, stream>>>(wg1, wg2, wk, wq, wvT, tmap, v_mask, v, out);
}

// Round 3
// 428.869 us; speedup vs baseline: 1.0907x; 1.0248x over previous
//
#include <hip/hip_runtime.h>
#include <math.h>

#define BS 64
#define NOBJ 256
#define TTOK 32
#define DIM 512
#define NREL 8
#define DKK 64
#define NN 65536

typedef __attribute__((ext_vector_type(8))) short bf16x8;
typedef __attribute__((ext_vector_type(4))) float f32x4;

__device__ __forceinline__ unsigned short f2bf(float x) {
    union { float f; unsigned int u; } c; c.f = x;
    unsigned int u = c.u;
    return (unsigned short)((u + 0x7fffu + ((u >> 16) & 1u)) >> 16);
}
__device__ __forceinline__ float bf2f(unsigned short h) {
    union { unsigned int u; float f; } c; c.u = ((unsigned int)h) << 16;
    return c.f;
}
// async 16B global -> LDS (wave-uniform LDS base + lane*16)
__device__ __forceinline__ void gl2lds16(const unsigned short* g, unsigned short* l) {
    __builtin_amdgcn_global_load_lds((const __attribute__((address_space(1))) void*)g,
                                     (__attribute__((address_space(3))) void*)l, 16, 0, 0);
}

// ---------------- K1: text summary -> t_summary (bf16, 64x512) ----------------
__global__ void k_text(const float* __restrict__ tt, const float* __restrict__ t_mask,
                       const float* __restrict__ tc_w, const float* __restrict__ tc_b,
                       unsigned short* __restrict__ ts_bf) {
    int b = blockIdx.x;
    int tid = threadIdx.x;
    __shared__ float red[TTOK][8];
    __shared__ float sc[TTOK];
    {
        int tok = tid >> 3, seg = tid & 7;
        const float* tp = tt + (size_t)(b * TTOK + tok) * DIM + seg * 64;
        const float* wp = tc_w + seg * 64;
        float s = 0.f;
#pragma unroll
        for (int i = 0; i < 16; ++i) {
            float4 a = *(const float4*)(tp + i * 4);
            float4 w = *(const float4*)(wp + i * 4);
            s += a.x * w.x + a.y * w.y + a.z * w.z + a.w * w.w;
        }
        red[tok][seg] = s;
    }
    __syncthreads();
    if (tid < TTOK) {
        float s = 0.f;
#pragma unroll
        for (int i = 0; i < 8; ++i) s += red[tid][i];
        float m = t_mask[b * TTOK + tid];
        float tc = m * s + tc_b[0];
        float sig = 1.f / (1.f + __expf(-tc));
        sc[tid] = (m != 0.f) ? m * sig : 0.f;
    }
    __syncthreads();
    for (int d = tid; d < DIM; d += 256) {
        float acc = 0.f;
#pragma unroll
        for (int tok = 0; tok < TTOK; ++tok)
            acc += tt[(size_t)(b * TTOK + tok) * DIM + d] * sc[tok];
        ts_bf[b * DIM + d] = f2bf(acc);
    }
}

// ---------------- K3a: convert v,b to bf16 ----------------
__global__ void k_convert(const float* __restrict__ v, const float* __restrict__ b,
                          unsigned short* __restrict__ v_bf, unsigned short* __restrict__ b_bf) {
    const float* src = blockIdx.y ? b : v;
    unsigned short* dst = blockIdx.y ? b_bf : v_bf;
    size_t i = ((size_t)blockIdx.x * 256 + threadIdx.x) * 4;
    float4 a = *(const float4*)(src + i);
    ushort4 o;
    o.x = f2bf(a.x); o.y = f2bf(a.y); o.z = f2bf(a.z); o.w = f2bf(a.w);
    *(ushort4*)(dst + i) = o;
}

// ---------------- K3b: weights -> WT (2560 cols x 512 k, bf16, k-contiguous) ----------------
__global__ void k_wt(const float* __restrict__ w0, const float* __restrict__ w1,
                     const float* __restrict__ w2, const float* __restrict__ w3,
                     const float* __restrict__ w4, unsigned short* __restrict__ WT) {
    int wsel = blockIdx.z;
    const float* W = wsel == 0 ? w0 : wsel == 1 ? w1 : wsel == 2 ? w2 : wsel == 3 ? w3 : w4;
    int k0 = blockIdx.x * 64, d0 = blockIdx.y * 64;
    __shared__ float tile[64][65];
    int tid = threadIdx.x;
#pragma unroll
    for (int p = 0; p < 16; ++p) {
        int lin = p * 256 + tid;
        int kk = lin >> 6, dd = lin & 63;
        tile[kk][dd] = W[(size_t)(k0 + kk) * DIM + d0 + dd];
    }
    __syncthreads();
    unsigned short* outp = WT + (size_t)wsel * DIM * DIM;
#pragma unroll
    for (int p = 0; p < 16; ++p) {
        int lin = p * 256 + tid;
        int dd = lin >> 6, kk = lin & 63;
        outp[(size_t)(d0 + dd) * DIM + k0 + kk] = f2bf(tile[kk][dd]);
    }
}

// ---------------- K2: tmap = relu(ts @ tmap_w + tmap_b), (64 x 65536) -> bf16 ----------------
// v2: float4 global loads (4x fewer instrs), packed b32 LDS writes, XOR-swizzled transpose,
// double-buffered Bt with register prefetch, ONE barrier per k-step (16 vs 32).
// Swizzle: global row kk of col stored at pos = kk ^ 8*((col>>3)&3); b128 read of rows
// q*8..q*8+7 reads pos (q^x)*8..+7 (contiguous, 16B-aligned since row stride 80B = 5*16B).
__launch_bounds__(256)
__global__ void k_tmap(const unsigned short* __restrict__ ts_bf,
                       const float* __restrict__ tmap_w, const float* __restrict__ tmap_b,
                       unsigned short* __restrict__ tmap) {
    int j0 = blockIdx.x * 64;
    int tid = threadIdx.x;
    int w = tid >> 6, lane = tid & 63, q = lane >> 4, li = lane & 15;
    __shared__ __align__(16) unsigned short Bt[2][64][40];
    f32x4 acc[4];
#pragma unroll
    for (int ct = 0; ct < 4; ++ct) acc[ct] = (f32x4){0.f, 0.f, 0.f, 0.f};

    // staging assignment: thread -> row-pair rp (2 k-rows), 4 cols at c4*4
    int rp = tid >> 4, c4 = tid & 15;
    const float* gsrc = tmap_w + (size_t)(2 * rp) * NN + j0 + c4 * 4;
    float4 f0 = *(const float4*)(gsrc);
    float4 f1 = *(const float4*)(gsrc + NN);

    for (int ks = 0; ks < 16; ++ks) {
        int cur = ks & 1;
        // write staged regs (k-rows 2rp,2rp+1 of block ks) into Bt[cur], packed as b32
        {
            float lo[4] = {f0.x, f0.y, f0.z, f0.w};
            float hi[4] = {f1.x, f1.y, f1.z, f1.w};
#pragma unroll
            for (int e = 0; e < 4; ++e) {
                int col = c4 * 4 + e;
                int x = (col >> 3) & 3;
                int pos = (2 * rp) ^ (x * 8);
                unsigned int pk = (unsigned int)f2bf(lo[e]) | ((unsigned int)f2bf(hi[e]) << 16);
                *(unsigned int*)(&Bt[cur][col][pos]) = pk;
            }
        }
        // prefetch next k-block into regs (latency hidden under barrier + MFMA)
        if (ks < 15) {
            const float* g = gsrc + (size_t)(ks + 1) * 32 * NN;
            f0 = *(const float4*)(g);
            f1 = *(const float4*)(g + NN);
        }
        __syncthreads();
        int k0 = ks * 32;
        bf16x8 a = *(const bf16x8*)(ts_bf + (size_t)(w * 16 + li) * DIM + k0 + q * 8);
#pragma unroll
        for (int ct = 0; ct < 4; ++ct) {
            int col = ct * 16 + li;
            int x = (col >> 3) & 3;
            bf16x8 bb = *(const bf16x8*)(&Bt[cur][col][(q ^ x) * 8]);
            acc[ct] = __builtin_amdgcn_mfma_f32_16x16x32_bf16(a, bb, acc[ct], 0, 0, 0);
        }
        // no second barrier: next iter writes Bt[cur^1]; reads of Bt[cur^1] (iter ks-1)
        // are ordered before this iter's writes by the barrier above.
    }
#pragma unroll
    for (int ct = 0; ct < 4; ++ct) {
        int j = j0 + ct * 16 + li;
        float bias = tmap_b[j];
#pragma unroll
        for (int i = 0; i < 4; ++i) {
            int bb = w * 16 + q * 4 + i;
            float val = fmaxf(acc[ct][i] + bias, 0.f);
            tmap[(size_t)bb * NN + j] = f2bf(val);
        }
    }
}

// ---------------- K4: 5 projections, BK=64, double-buffered DMA staging (2-phase) ----------
// v2: LDS double-buffer (64 KB, 2 blocks/CU). Per k-step: issue next step's 8 global_load_lds
// into the other buffer, compute current, ONE __syncthreads (its vmcnt drain covers loads
// that had a full compute phase in flight). Removes the per-k-step serial latency drain.
__launch_bounds__(256)
__global__ void k_proj(const unsigned short* __restrict__ v_bf, const unsigned short* __restrict__ b_bf,
                       const unsigned short* __restrict__ WT,
                       const float* __restrict__ bias0, const float* __restrict__ bias1,
                       const float* __restrict__ bias2, const float* __restrict__ bias3,
                       const float* __restrict__ bias4, const float* __restrict__ v_mask,
                       unsigned short* __restrict__ wg1, unsigned short* __restrict__ wg2,
                       unsigned short* __restrict__ wk, unsigned short* __restrict__ wq,
                       unsigned short* __restrict__ wvT) {
    int bx = blockIdx.x;
    int by = blockIdx.y;
    int m0 = bx * 128;
    int wsel = by >> 2;
    const unsigned short* A = (wsel < 2) ? b_bf : v_bf;
    int tid = threadIdx.x;
    int w = tid >> 6, lane = tid & 63, q = lane >> 4, li = lane & 15;
    int rh = w & 1, ch = w >> 1;

    __shared__ __align__(16) unsigned short smem[32768];  // 2 x (As 8192 + Bs 8192) shorts

    f32x4 acc[4][4];
#pragma unroll
    for (int rt = 0; rt < 4; ++rt)
#pragma unroll
        for (int ct = 0; ct < 4; ++ct) acc[rt][ct] = (f32x4){0.f, 0.f, 0.f, 0.f};

    const unsigned short* WTb = WT + (size_t)by * 128 * DIM;

    int rl = lane >> 3;
    int lseg = (lane & 7) ^ rl;
    const unsigned short* Agp[4];
    const unsigned short* Bgp[4];
    unsigned short* Alp[4];
    unsigned short* Blp[4];
#pragma unroll
    for (int c4 = 0; c4 < 4; ++c4) {
        int c = w * 4 + c4;
        int row = c * 8 + rl;
        Agp[c4] = A + (size_t)(m0 + row) * DIM + lseg * 8;
        Bgp[c4] = WTb + (size_t)row * DIM + lseg * 8;
        Alp[c4] = smem + c * 512;            // buf0 A
        Blp[c4] = smem + 8192 + c * 512;     // buf0 B
    }

    int arow = (rh * 64 + li) * 64;
    int brow = (ch * 64 + li) * 64;
    int sseg0 = ((q) ^ (li & 7)) * 8;
    int sseg1 = ((4 + q) ^ (li & 7)) * 8;

    // prologue: stage k-step 0 into buffer 0
#pragma unroll
    for (int c4 = 0; c4 < 4; ++c4) {
        gl2lds16(Agp[c4], Alp[c4]);
        gl2lds16(Bgp[c4], Blp[c4]);
    }
    __syncthreads();

    for (int ks = 0; ks < 8; ++ks) {
        int cur = ks & 1;
        if (ks < 7) {
            int k0 = (ks + 1) * 64;
            int noff = (cur ^ 1) * 16384;
#pragma unroll
            for (int c4 = 0; c4 < 4; ++c4) {
                gl2lds16(Agp[c4] + k0, Alp[c4] + noff);
                gl2lds16(Bgp[c4] + k0, Blp[c4] + noff);
            }
        }
        const unsigned short* Asb = smem + cur * 16384;
        const unsigned short* Bsb = Asb + 8192;
#pragma unroll
        for (int j = 0; j < 2; ++j) {
            int sseg = j ? sseg1 : sseg0;
            bf16x8 af[4], bfr[4];
#pragma unroll
            for (int rt = 0; rt < 4; ++rt)
                af[rt] = *(const bf16x8*)(Asb + arow + rt * 1024 + sseg);
#pragma unroll
            for (int ct = 0; ct < 4; ++ct)
                bfr[ct] = *(const bf16x8*)(Bsb + brow + ct * 1024 + sseg);
#pragma unroll
            for (int rt = 0; rt < 4; ++rt)
#pragma unroll
                for (int ct = 0; ct < 4; ++ct)
                    acc[rt][ct] = __builtin_amdgcn_mfma_f32_16x16x32_bf16(af[rt], bfr[ct], acc[rt][ct], 0, 0, 0);
        }
        __syncthreads();   // drains next-step DMA (in flight during compute) + buffer-reuse guard
    }

    const float* bias = wsel == 0 ? bias0 : wsel == 1 ? bias1 : wsel == 2 ? bias2 : wsel == 3 ? bias3 : bias4;
    int dblk = (by & 3) * 128;

    unsigned short (*T)[136] = (unsigned short (*)[136])smem;
    if (wsel < 4) {
#pragma unroll
        for (int ct = 0; ct < 4; ++ct) {
            int d = dblk + ch * 64 + ct * 16 + li;
            float bs = bias[d];
#pragma unroll
            for (int rt = 0; rt < 4; ++rt) {
#pragma unroll
                for (int i = 0; i < 4; ++i) {
                    int nl = rh * 64 + rt * 16 + q * 4 + i;
                    float val = acc[rt][ct][i] + bs;
                    if (wsel < 2) val *= v_mask[m0 + nl];
                    T[nl][ch * 64 + ct * 16 + li] = f2bf(val);
                }
            }
        }
        __syncthreads();
        unsigned short* dstb = wsel == 0 ? wg1 : wsel == 1 ? wg2 : wsel == 2 ? wk : wq;
        int dc = lane & 15;
#pragma unroll
        for (int rr = 0; rr < 8; ++rr) {
            int outer = w * 32 + rr * 4 + (lane >> 4);
            *(bf16x8*)(dstb + (size_t)(m0 + outer) * DIM + dblk + dc * 8) =
                *(const bf16x8*)(&T[outer][dc * 8]);
        }
    } else {
#pragma unroll
        for (int ct = 0; ct < 4; ++ct) {
            int dl = ch * 64 + ct * 16 + li;
            float bs = bias[dblk + dl];
#pragma unroll
            for (int rt = 0; rt < 4; ++rt) {
#pragma unroll
                for (int i = 0; i < 4; ++i) {
                    int nl = rh * 64 + rt * 16 + q * 4 + i;
                    T[dl][nl] = f2bf(acc[rt][ct][i] + bs);
                }
            }
        }
        __syncthreads();
        int b = m0 >> 8, nbase = m0 & 255;
        int dc = lane & 15;
#pragma unroll
        for (int rr = 0; rr < 8; ++rr) {
            int outer = w * 32 + rr * 4 + (lane >> 4);
            int d = dblk + outer;
            int r = d >> 6, dk = d & 63;
            *(bf16x8*)(wvT + ((size_t)(b * NREL + r) * DKK + dk) * NOBJ + nbase + dc * 8) =
                *(const bf16x8*)(&T[outer][dc * 8]);
        }
    }
}

// ---------------- K5: attention, software-pipelined (PV deferred one iteration) ----------
// Grid 1024 (known-good block shape): block = (b, r, half of 128 rows), 4 waves x 32 rows.
// Per iter j: loads(j) -> PV(j-1) [reads P_lds written a full iter ago, vb loaded a full
// iter ago] -> QK(j) -> softmax(j) -> P_lds[j&1] -> issue vb(j). Breaks the in-iteration
// ds_write->lgkmcnt->ds_read->MFMA serialization that dominated the latency chain.
__launch_bounds__(256)
__global__ void k_attn(const unsigned short* __restrict__ wg1, const unsigned short* __restrict__ wg2,
                       const unsigned short* __restrict__ wk, const unsigned short* __restrict__ wq,
                       const unsigned short* __restrict__ wvT,
                       const unsigned short* __restrict__ tmap, const float* __restrict__ v_mask,
                       const float* __restrict__ v, float* __restrict__ out) {
    int L = blockIdx.x;
    int x = L & 7, jj = L >> 3;
    int b = x + 8 * (jj >> 4);           // same-b blocks share launch-id mod 8 (XCD locality)
    int inner = jj & 15;
    int r = inner >> 1, half = inner & 1;
    int br = b * NREL + r;

    int tid = threadIdx.x;
    int w = tid >> 6, lane = tid & 63, q = lane >> 4, li = lane & 15;
    int n0 = half * 128 + w * 32;        // wave's 32 rows

    __shared__ __align__(16) unsigned short P_lds[4][2][32][36];

    // A-fragments: wg1/wk rows (32 x 64k)
    bf16x8 ag[2][2], ak[2][2];
    {
        const unsigned short* g1b = wg1 + (size_t)(b * NOBJ + n0 + li) * DIM + r * DKK + q * 8;
        const unsigned short* kb  = wk  + (size_t)(b * NOBJ + n0 + li) * DIM + r * DKK + q * 8;
#pragma unroll
        for (int rt = 0; rt < 2; ++rt)
#pragma unroll
            for (int kt = 0; kt < 2; ++kt) {
                ag[rt][kt] = *(const bf16x8*)(g1b + (size_t)rt * 16 * DIM + kt * 32);
                ak[rt][kt] = *(const bf16x8*)(kb + (size_t)rt * 16 * DIM + kt * 32);
            }
    }

    f32x4 O[2][4];
    float lsum[2][4];
#pragma unroll
    for (int rt = 0; rt < 2; ++rt) {
#pragma unroll
        for (int dt = 0; dt < 4; ++dt) O[rt][dt] = (f32x4){0.f, 0.f, 0.f, 0.f};
#pragma unroll
        for (int i = 0; i < 4; ++i) lsum[rt][i] = 0.f;
    }

    const unsigned short* tb = tmap + ((size_t)b << 16) + (n0 + q * 4) * 256 + li;

    bf16x8 vbp[4];                       // vb of iter j, consumed by PV at iter j+1

    // ---- QK+softmax body (emits P_lds[buf] for column tile c0) ----
    auto qk_softmax = [&](int j, int c0, int buf) {
        bf16x8 bg[2][2], bq[2][2];
        {
            const unsigned short* g2b = wg2 + (size_t)(b * NOBJ + c0 + li) * DIM + r * DKK + q * 8;
            const unsigned short* qb  = wq  + (size_t)(b * NOBJ + c0 + li) * DIM + r * DKK + q * 8;
#pragma unroll
            for (int ct = 0; ct < 2; ++ct)
#pragma unroll
                for (int kt = 0; kt < 2; ++kt) {
                    bg[ct][kt] = *(const bf16x8*)(g2b + (size_t)ct * 16 * DIM + kt * 32);
                    bq[ct][kt] = *(const bf16x8*)(qb + (size_t)ct * 16 * DIM + kt * 32);
                }
        }
        float vm0 = v_mask[b * NOBJ + c0 + li];
        float vm1 = v_mask[b * NOBJ + c0 + 16 + li];

#pragma unroll
        for (int rt = 0; rt < 2; ++rt) {
#pragma unroll
            for (int ct = 0; ct < 2; ++ct) {
                f32x4 aG = (f32x4){0.f, 0.f, 0.f, 0.f};
                f32x4 aK = (f32x4){0.f, 0.f, 0.f, 0.f};
#pragma unroll
                for (int kt = 0; kt < 2; ++kt) {
                    aG = __builtin_amdgcn_mfma_f32_16x16x32_bf16(ag[rt][kt], bg[ct][kt], aG, 0, 0, 0);
                    aK = __builtin_amdgcn_mfma_f32_16x16x32_bf16(ak[rt][kt], bq[ct][kt], aK, 0, 0, 0);
                }
                float vm = ct ? vm1 : vm0;
#pragma unroll
                for (int i = 0; i < 4; ++i) {
                    // p = max(relu(G)+tmap, 1e-6) * exp(dot/8); exact softmax after /l.
                    float tm = bf2f(tb[(rt * 16 + i) * 256 + c0 + ct * 16]);
                    float g = fmaxf(fmaxf(aG[i], 0.f) + tm, 1e-6f);
                    float p = (vm == 0.f) ? 0.f : g * __expf(aK[i] * 0.125f);
                    lsum[rt][i] += p;
                    P_lds[w][buf][rt * 16 + q * 4 + i][ct * 16 + li] = f2bf(p);
                }
            }
        }
    };
    // ---- vb issue for tile c0 (consumed next iteration) ----
    auto load_vb = [&](int c0) {
#pragma unroll
        for (int dt = 0; dt < 4; ++dt)
            vbp[dt] = *(const bf16x8*)(wvT + (size_t)(br * DKK + dt * 16 + li) * NOBJ + c0 + q * 8);
    };
    // ---- PV for tile whose P sits in P_lds[buf], vb in vbp ----
    auto pv = [&](int buf) {
        bf16x8 pa[2];
#pragma unroll
        for (int rt = 0; rt < 2; ++rt)
            pa[rt] = *(const bf16x8*)(&P_lds[w][buf][rt * 16 + li][q * 8]);
#pragma unroll
        for (int rt = 0; rt < 2; ++rt)
#pragma unroll
            for (int dt = 0; dt < 4; ++dt)
                O[rt][dt] = __builtin_amdgcn_mfma_f32_16x16x32_bf16(pa[rt], vbp[dt], O[rt][dt], 0, 0, 0);
    };

    // prologue: tile 0
    qk_softmax(0, 0, 0);
    load_vb(0);

    for (int j = 1; j < 8; ++j) {
        int c0 = j * 32;
        pv((j - 1) & 1);                 // PV(j-1): all operands one iteration old
        qk_softmax(j, c0, j & 1);
        load_vb(c0);
    }
    pv(1);                               // PV(7)

    // epilogue: reduce l over the 16 li lanes, then out = O/l + v
#pragma unroll
    for (int rt = 0; rt < 2; ++rt) {
        float linv[4];
#pragma unroll
        for (int i = 0; i < 4; ++i) {
            float s = lsum[rt][i];
            s += __shfl_xor(s, 1);
            s += __shfl_xor(s, 2);
            s += __shfl_xor(s, 4);
            s += __shfl_xor(s, 8);
            linv[i] = 1.f / s;
        }
#pragma unroll
        for (int dt = 0; dt < 4; ++dt) {
#pragma unroll
            for (int i = 0; i < 4; ++i) {
                int n = n0 + rt * 16 + q * 4 + i;
                size_t idx = (size_t)(b * NOBJ + n) * DIM + r * DKK + dt * 16 + li;
                out[idx] = O[rt][dt][i] * linv[i] + v[idx];
            }
        }
    }
}

extern "C" void kernel_launch(void* const* d_in, const int* in_sizes, int n_in,
                              void* d_out, int out_size, void* d_ws, size_t ws_size,
                              hipStream_t stream) {
    const float* v      = (const float*)d_in[0];
    const float* b      = (const float*)d_in[1];
    const float* v_mask = (const float*)d_in[2];
    const float* t      = (const float*)d_in[3];
    const float* t_mask = (const float*)d_in[4];
    const float* WG1_w  = (const float*)d_in[5];
    const float* WG1_b  = (const float*)d_in[6];
    const float* WG2_w  = (const float*)d_in[7];
    const float* WG2_b  = (const float*)d_in[8];
    const float* WK_w   = (const float*)d_in[9];
    const float* WK_b   = (const float*)d_in[10];
    const float* WQ_w   = (const float*)d_in[11];
    const float* WQ_b   = (const float*)d_in[12];
    const float* WV_w   = (const float*)d_in[13];
    const float* WV_b   = (const float*)d_in[14];
    const float* tc_w   = (const float*)d_in[15];
    const float* tc_b   = (const float*)d_in[16];
    const float* tmap_w = (const float*)d_in[17];
    const float* tmap_b = (const float*)d_in[18];
    float* out = (float*)d_out;

    char* ws = (char*)d_ws;
    size_t off = 0;
    auto alloc = [&](size_t bytes) {
        void* p = ws + off;
        off += (bytes + 255) & ~(size_t)255;
        return p;
    };
    unsigned short* ts_bf = (unsigned short*)alloc((size_t)BS * DIM * 2);
    unsigned short* tmap  = (unsigned short*)alloc((size_t)BS * NN * 2);
    unsigned short* v_bf  = (unsigned short*)alloc((size_t)BS * NOBJ * DIM * 2);
    unsigned short* b_bf  = (unsigned short*)alloc((size_t)BS * NOBJ * DIM * 2);
    unsigned short* WT    = (unsigned short*)alloc((size_t)5 * DIM * DIM * 2);
    unsigned short* wg1   = (unsigned short*)alloc((size_t)BS * NOBJ * DIM * 2);
    unsigned short* wg2   = (unsigned short*)alloc((size_t)BS * NOBJ * DIM * 2);
    unsigned short* wk    = (unsigned short*)alloc((size_t)BS * NOBJ * DIM * 2);
    unsigned short* wq    = (unsigned short*)alloc((size_t)BS * NOBJ * DIM * 2);
    unsigned short* wvT   = (unsigned short*)alloc((size_t)BS * NOBJ * DIM * 2);

    k_text<<<dim3(BS), dim3(256), 0, stream>>>(t, t_mask, tc_w, tc_b, ts_bf);
    k_convert<<<dim3(8192, 2), dim3(256), 0, stream>>>(v, b, v_bf, b_bf);
    k_wt<<<dim3(8, 8, 5), dim3(256), 0, stream>>>(WG1_w, WG2_w, WK_w, WQ_w, WV_w, WT);
    k_tmap<<<dim3(1024), dim3(256), 0, stream>>>(ts_bf, tmap_w, tmap_b, tmap);
    k_proj<<<dim3(128, 20), dim3(256), 0, stream>>>(v_bf, b_bf, WT,
                                                    WG1_b, WG2_b, WK_b, WQ_b, WV_b, v_mask,
                                                    wg1, wg2, wk, wq, wvT);
    k_attn<<<dim3(1024), dim3(256), 0, stream>>>(wg1, wg2, wk, wq, wvT, tmap, v_mask, v, out);
}